// Round 5
// baseline (800.236 us; speedup 1.0000x reference)
//
#include <hip/hip_runtime.h>
#include <hip/hip_cooperative_groups.h>

namespace cg = cooperative_groups;

// ---------------------------------------------------------------------------
// Triplane sample + 4-layer MLP, N=1e6 points. 3 dispatches:
//   D1 prep_kernel: [blocks 0..3071] transpose planes f32->f16 (x256, chan-
//       contiguous); [3072..3215] weights f32->f16; [3216..3343] zero hist.
//   D2 sort_coop (cooperative, 1024x256): Morton hist (coords+keys cached in
//       regs) -> grid.sync -> 2-level scan -> grid.sync -> scatter from regs.
//   D3 fused_kernel: sample 128 pts/block -> LDS feats -> pair-split MFMA MLP
//       -> out[orig_idx].
// Scale S=256 keeps f16 in normal range; epilogues add S*b in fp32; final
// layer divides by S in fp32.
//
// R1 (FAILED, 294us): 32-pt waves -> ILP collapse + 2x W traffic.
// R2 (NEUTRAL): pair-split 4 blk/CU; by-ref acc spilled (WRITE 70MB).
// R3 (NEUTRAL, 177us): de-spilled; mlp latency-chain bound, not occupancy.
// R4 (WIN, 598->509us): fused sample+MLP (238us vs 327us for the pair).
// R5: the constant ~271us tail = 6 small dependent dispatches (~85us of
//   real work + gaps). Collapse to 2 preprocessing dispatches; cooperative
//   hist/scan/scatter also removes a 12MB coords re-read + key recompute.
// ---------------------------------------------------------------------------

#define SF 256.0f
#define HPAD 136  // halves per point-row in LDS H (128 + 8 pad), 16B aligned
#define FSTR 40   // halves per point-row for LDS feats overlay (32 + 8 pad)

typedef _Float16 half8 __attribute__((ext_vector_type(8)));
typedef _Float16 half4_t __attribute__((ext_vector_type(4)));
typedef float f32x4 __attribute__((ext_vector_type(4)));
typedef unsigned int u32x4 __attribute__((ext_vector_type(4)));

// ---------------- Morton key ----------------
__device__ inline unsigned spread5(unsigned v) {
  v &= 31u;
  v = (v | (v << 8)) & 0x100Fu;
  v = (v | (v << 4)) & 0x10C3u;
  v = (v | (v << 2)) & 0x1249u;
  return v;
}
__device__ inline unsigned cellkey(float x, float y, float z) {
  int qx = min(31, max(0, (int)((x + 1.0f) * 16.0f)));
  int qy = min(31, max(0, (int)((y + 1.0f) * 16.0f)));
  int qz = min(31, max(0, (int)((z + 1.0f) * 16.0f)));
  return spread5((unsigned)qx) | (spread5((unsigned)qy) << 1) |
         (spread5((unsigned)qz) << 2);
}

// ---------------- D1: prep (transpose + weights + zero hist) ----------------
__global__ __launch_bounds__(256) void prep_kernel(
    const float* __restrict__ planes, _Float16* __restrict__ ph,
    const float* __restrict__ w0, const float* __restrict__ w1,
    const float* __restrict__ w2, _Float16* __restrict__ w0h,
    _Float16* __restrict__ w1h, _Float16* __restrict__ w2h,
    unsigned* __restrict__ hist) {
  int bid = blockIdx.x;
  if (bid < 3072) {
    // plane transpose+convert+scale: 3*2^18 threads exactly
    int t = bid * 256 + threadIdx.x;
    int pid = t >> 18;
    int rem = t & ((1 << 18) - 1);              // y*512 + x
    const float* src = planes + ((size_t)pid << 23) + rem;  // [pid][c][y][x]
    union { _Float16 h[32]; u32x4 v[4]; } u;
#pragma unroll
    for (int c = 0; c < 32; c++)
      u.h[c] = (_Float16)(src[(size_t)c << 18] * SF);
    u32x4* dst = reinterpret_cast<u32x4*>(ph + ((size_t)t << 5));
#pragma unroll
    for (int i = 0; i < 4; i++) dst[i] = u.v[i];
  } else if (bid < 3216) {
    // weights f32 -> f16: 36864 threads exactly
    int t = (bid - 3072) * 256 + threadIdx.x;
    if (t < 4096) w0h[t] = (_Float16)w0[t];
    else if (t < 20480) w1h[t - 4096] = (_Float16)w1[t - 4096];
    else w2h[t - 20480] = (_Float16)w2[t - 20480];
  } else {
    // zero histogram: 128 blocks * 256 = 32768 exactly
    int t = (bid - 3216) * 256 + threadIdx.x;
    hist[t] = 0u;
  }
}

// ---------------- D2: cooperative hist + scan + scatter ----------------
// 1024 blocks x 256 threads (4 blocks/CU, trivially co-resident).
// Each thread owns up to 4 points (coords+keys cached in registers).
__global__ __launch_bounds__(256, 4) void sort_coop(
    const float* __restrict__ coords, unsigned* __restrict__ hist,
    unsigned* __restrict__ cursor, unsigned* __restrict__ blocksum,
    unsigned* __restrict__ blockoff, float4* __restrict__ sorted, int npts) {
  cg::grid_group grid = cg::this_grid();
  __shared__ unsigned s[256];
  int gtid = blockIdx.x * 256 + threadIdx.x;  // 262144 threads

  // ---- phase A: histogram; cache points in regs ----
  float px[4], py[4], pz[4];
  unsigned key[4];
#pragma unroll
  for (int i = 0; i < 4; i++) {
    long p = (long)i * 262144 + gtid;
    if (p < npts) {
      px[i] = coords[3 * p + 0];
      py[i] = coords[3 * p + 1];
      pz[i] = coords[3 * p + 2];
      key[i] = cellkey(px[i], py[i], pz[i]);
      atomicAdd(&hist[key[i]], 1u);
    } else {
      key[i] = 0xFFFFFFFFu;
    }
  }
  grid.sync();

  // ---- phase B1: blocks 0..127 exclusive-scan their 256-entry chunk ----
  if (blockIdx.x < 128) {
    int t = threadIdx.x;
    int base = blockIdx.x * 256;
    unsigned v = hist[base + t];
    s[t] = v;
    __syncthreads();
    for (int off = 1; off < 256; off <<= 1) {
      unsigned u = (t >= off) ? s[t - off] : 0u;
      __syncthreads();
      s[t] += u;
      __syncthreads();
    }
    cursor[base + t] = s[t] - v;  // within-chunk exclusive
    if (t == 255) blocksum[blockIdx.x] = s[255];
  }
  grid.sync();

  // ---- phase B2: block 0 exclusive-scans the 128 chunk totals ----
  if (blockIdx.x == 0) {
    int t = threadIdx.x;
    unsigned v2 = (t < 128) ? blocksum[t] : 0u;
    s[t] = v2;
    __syncthreads();
    for (int off = 1; off < 128; off <<= 1) {
      unsigned u = (t >= off) ? s[t - off] : 0u;
      __syncthreads();
      s[t] += u;
      __syncthreads();
    }
    if (t < 128) blockoff[t] = s[t] - v2;
  }
  grid.sync();

  // ---- phase C: scatter from cached regs ----
#pragma unroll
  for (int i = 0; i < 4; i++) {
    long p = (long)i * 262144 + gtid;
    if (p < npts) {
      unsigned k = key[i];
      unsigned pos = atomicAdd(&cursor[k], 1u) + blockoff[k >> 8];
      float4 v;
      v.x = px[i]; v.y = py[i]; v.z = pz[i];
      v.w = __uint_as_float((unsigned)p);
      sorted[pos] = v;
    }
  }
}

// ---------------- bilinear sampling: 16 channels (hf selects half) --------
__device__ __attribute__((always_inline)) inline void samp16(
    const _Float16* __restrict__ pl, float X, float Y, int hf, float* acc) {
  float fx = (X + 1.0f) * 0.5f * 511.0f;
  float fy = (Y + 1.0f) * 0.5f * 511.0f;
  float x0f = floorf(fx), y0f = floorf(fy);
  float wx1 = fx - x0f, wy1 = fy - y0f;
  float wx0 = 1.0f - wx1, wy0 = 1.0f - wy1;
  int x0 = (int)x0f, y0 = (int)y0f;
  int x1 = x0 + 1, y1 = y0 + 1;
  float vx0 = (x0 >= 0 && x0 < 512) ? 1.0f : 0.0f;
  float vx1 = (x1 >= 0 && x1 < 512) ? 1.0f : 0.0f;
  float vy0 = (y0 >= 0 && y0 < 512) ? 1.0f : 0.0f;
  float vy1 = (y1 >= 0 && y1 < 512) ? 1.0f : 0.0f;
  int xc0 = min(max(x0, 0), 511), xc1 = min(max(x1, 0), 511);
  int yc0 = min(max(y0, 0), 511), yc1 = min(max(y1, 0), 511);
  float w00 = wx0 * wy0 * vx0 * vy0, w10 = wx1 * wy0 * vx1 * vy0;
  float w01 = wx0 * wy1 * vx0 * vy1, w11 = wx1 * wy1 * vx1 * vy1;
  const _Float16* p00 = pl + ((((size_t)yc0 << 9) + xc0) << 5) + hf * 16;
  const _Float16* p10 = pl + ((((size_t)yc0 << 9) + xc1) << 5) + hf * 16;
  const _Float16* p01 = pl + ((((size_t)yc1 << 9) + xc0) << 5) + hf * 16;
  const _Float16* p11 = pl + ((((size_t)yc1 << 9) + xc1) << 5) + hf * 16;
#pragma unroll
  for (int ch = 0; ch < 2; ch++) {
    union { u32x4 v; _Float16 h[8]; } a, b, c, d;
    a.v = *reinterpret_cast<const u32x4*>(p00 + ch * 8);
    b.v = *reinterpret_cast<const u32x4*>(p10 + ch * 8);
    c.v = *reinterpret_cast<const u32x4*>(p01 + ch * 8);
    d.v = *reinterpret_cast<const u32x4*>(p11 + ch * 8);
#pragma unroll
    for (int j = 0; j < 8; j++) {
      acc[ch * 8 + j] += w00 * (float)a.h[j] + w10 * (float)b.h[j] +
                         w01 * (float)c.h[j] + w11 * (float)d.h[j];
    }
  }
}

// ---------------- D3: fused sample + MLP ----------------
// Block = 256 threads = 2 pairs = 128 points; LDS 34816 B -> 4 blocks/CU.
// Phase 1: 2 threads/pt sample 16ch each -> LDS feats (stride FSTR halves).
// Phase 2: pair-split MLP -- 2 waves share one 64-pt H buffer; wave w owns
//   hidden rows 64w..64w+63. Layer body is a MACRO (no call boundary), B
//   preloaded, per-mt fused epilogue: no spill, peak ~105 VGPR < 128 cap.
__device__ __attribute__((always_inline)) inline half8 ld16(const _Float16* p) {
  return *reinterpret_cast<const half8*>(p);
}

#define LAYER_PAIR(Wg, bias)                                                   \
  {                                                                            \
    half8 Bf[4][4]; /* [nt][ks] : 64 regs */                                   \
    _Pragma("unroll") for (int nt = 0; nt < 4; nt++)                           \
    _Pragma("unroll") for (int ks = 0; ks < 4; ks++)                           \
        Bf[nt][ks] = ld16(&H[(nt * 16 + n16) * HPAD + ks * 32 + g * 8]);       \
    __syncthreads(); /* all H reads done; safe to overwrite */                 \
    _Pragma("unroll") for (int mt = 0; mt < 4; mt++) {                         \
      f32x4 acc[4];                                                            \
      _Pragma("unroll") for (int nt = 0; nt < 4; nt++) acc[nt] = Z4;           \
      _Pragma("unroll") for (int ks = 0; ks < 4; ks++) {                       \
        half8 A = ld16((Wg) + ((w * 4 + mt) * 16 + n16) * 128 + ks * 32 + g * 8); \
        _Pragma("unroll") for (int nt = 0; nt < 4; nt++)                       \
            acc[nt] = __builtin_amdgcn_mfma_f32_16x16x32_f16(A, Bf[nt][ks],    \
                                                             acc[nt], 0, 0, 0); \
      }                                                                        \
      int gm = w * 4 + mt;                                                     \
      f32x4 bb = *reinterpret_cast<const f32x4*>((bias) + gm * 16 + g * 4);    \
      _Pragma("unroll") for (int nt = 0; nt < 4; nt++) {                       \
        half4_t v;                                                             \
        _Pragma("unroll") for (int r = 0; r < 4; r++)                          \
            v[r] = (_Float16)fmaxf(acc[nt][r] + SF * bb[r], 0.0f);             \
        *reinterpret_cast<half4_t*>(                                           \
            &H[(nt * 16 + n16) * HPAD + gm * 16 + g * 4]) = v;                 \
      }                                                                        \
    }                                                                          \
    __syncthreads(); /* H writes visible to partner */                         \
  }

__global__ __launch_bounds__(256, 4) void fused_kernel(
    const float* __restrict__ coords, const float4* __restrict__ sorted,
    const _Float16* __restrict__ ph, const _Float16* __restrict__ w0h,
    const _Float16* __restrict__ w1h, const _Float16* __restrict__ w2h,
    const float* __restrict__ b0, const float* __restrict__ b1,
    const float* __restrict__ b2, const float* __restrict__ w3,
    const float* __restrict__ b3, float* __restrict__ out, int npts,
    int use_sorted) {
  __shared__ alignas(16) _Float16 hbuf[2][64 * HPAD];  // 34816 B -> 4 blk/CU
  int tid = threadIdx.x;
  // XCD swizzle: contiguous Morton range per XCD for plane L2 locality.
  int nb = gridDim.x, bid = blockIdx.x;
  int per = nb >> 3;
  int sb = (bid < (per << 3)) ? ((bid & 7) * per + (bid >> 3)) : bid;

  // ---- phase 1: sample 128 points; 2 threads/pt, 16 channels each ----
  {
    int ptl = tid >> 1, hf = tid & 1;  // waves 0,1 cover pair0; 2,3 pair1
    long pb = (long)sb * 128 + (ptl >> 6) * 64;
    if (pb + 64 > npts) pb = npts - 64;  // tail: duplicate identical work
    long pp = pb + (ptl & 63);
    float cx, cy, cz;
    if (use_sorted) {
      float4 f = sorted[pp];
      cx = f.x; cy = f.y; cz = f.z;
    } else {
      cx = coords[3 * pp + 0];
      cy = coords[3 * pp + 1];
      cz = coords[3 * pp + 2];
    }
    float acc[16];
#pragma unroll
    for (int c = 0; c < 16; c++) acc[c] = 0.0f;
    samp16(ph, cx, cy, hf, acc);                  // plane 0: (x, y)
    samp16(ph + (1u << 23), cy, cz, hf, acc);     // plane 1: (y, z)
    samp16(ph + (2u << 23), cx, cz, hf, acc);     // plane 2: (x, z)
    union { _Float16 h[16]; u32x4 v[2]; } u;
#pragma unroll
    for (int c = 0; c < 16; c++) u.h[c] = (_Float16)acc[c];
    _Float16* F = hbuf[ptl >> 6];
    // feats row stride FSTR=40 halves (80B: 16B-aligned, bank-uniform)
    *reinterpret_cast<u32x4*>(&F[(ptl & 63) * FSTR + hf * 16]) = u.v[0];
    *reinterpret_cast<u32x4*>(&F[(ptl & 63) * FSTR + hf * 16 + 8]) = u.v[1];
  }
  __syncthreads();  // feats visible to all waves

  // ---- phase 2: pair-split MLP ----
  int wv = tid >> 6, lane = tid & 63;
  int pair = wv >> 1, w = wv & 1;
  int n16 = lane & 15, g = lane >> 4;
  long base = (long)sb * 128 + pair * 64;
  if (base + 64 > npts) base = npts - 64;  // same clamp as phase 1
  _Float16* H = hbuf[pair];
  const f32x4 Z4 = {0.0f, 0.0f, 0.0f, 0.0f};

  // layer 0: C^T = W0(rows 64w..64w+63, x32) * feats^T(32x64); K=32.
  {
    half8 Bf[4];
#pragma unroll
    for (int nt = 0; nt < 4; nt++)
      Bf[nt] = ld16(&H[(nt * 16 + n16) * FSTR + g * 8]);  // LDS feats
    __syncthreads();  // feats reads done; epilogue may overwrite region
#pragma unroll
    for (int mt = 0; mt < 4; mt++) {
      half8 A = ld16(w0h + ((w * 4 + mt) * 16 + n16) * 32 + g * 8);
      f32x4 acc[4];
#pragma unroll
      for (int nt = 0; nt < 4; nt++)
        acc[nt] = __builtin_amdgcn_mfma_f32_16x16x32_f16(A, Bf[nt], Z4, 0, 0, 0);
      int gm = w * 4 + mt;
      f32x4 bb = *reinterpret_cast<const f32x4*>(b0 + gm * 16 + g * 4);
#pragma unroll
      for (int nt = 0; nt < 4; nt++) {
        half4_t v;
#pragma unroll
        for (int r = 0; r < 4; r++)
          v[r] = (_Float16)fmaxf(acc[nt][r] + SF * bb[r], 0.0f);
        *reinterpret_cast<half4_t*>(
            &H[(nt * 16 + n16) * HPAD + gm * 16 + g * 4]) = v;
      }
    }
    __syncthreads();  // H(L0) visible before L1 reads
  }

  LAYER_PAIR(w1h, b1)
  LAYER_PAIR(w2h, b2)

  // layer 3: out = dot(h2, w3)/S + b3, fp32 VALU.
  // Pair covers 64 pts; wave w takes pts w*32..+31. lane = pt' + 32*half;
  // each half does 8 of 16 chunks, reduce across halves via shfl_xor(32).
  int ptl3 = lane & 31, hh = lane >> 5;
  int pt = w * 32 + ptl3;
  float o = 0.0f;
#pragma unroll
  for (int ii = 0; ii < 8; ii++) {
    int i = hh * 8 + ii;
    half8 hv = ld16(&H[pt * HPAD + i * 8]);
#pragma unroll
    for (int j = 0; j < 8; j++) o += (float)hv[j] * w3[i * 8 + j];
  }
  o += __shfl_xor(o, 32);
  if (lane < 32) {
    unsigned idx = use_sorted ? __float_as_uint(sorted[base + pt].w)
                              : (unsigned)(base + pt);
    out[idx] = o * (1.0f / SF) + b3[0];
  }
}

// ---------------- launch ----------------
extern "C" void kernel_launch(void* const* d_in, const int* in_sizes, int n_in,
                              void* d_out, int out_size, void* d_ws, size_t ws_size,
                              hipStream_t stream) {
  const float* coords = (const float*)d_in[0];
  const float* planes = (const float*)d_in[1];
  const float* w0 = (const float*)d_in[2];
  const float* b0 = (const float*)d_in[3];
  const float* w1 = (const float*)d_in[4];
  const float* b1 = (const float*)d_in[5];
  const float* w2 = (const float*)d_in[6];
  const float* b2 = (const float*)d_in[7];
  const float* w3 = (const float*)d_in[8];
  const float* b3 = (const float*)d_in[9];
  float* out = (float*)d_out;
  int npts = in_sizes[0] / 3;  // 1,000,000

  // workspace layout (bytes):
  //   ph       @ 0          50,331,648
  //   w0h      @ 50331648   8,192
  //   w1h      @ 50339840   32,768
  //   w2h      @ 50372608   32,768
  //   hist     @ 50405376   131,072
  //   cursor   @ 50536448   131,072
  //   blocksum @ 50667520   512
  //   blockoff @ 50668032   512
  //   sorted   @ 50668544   npts*16
  char* ws = (char*)d_ws;
  _Float16* ph = (_Float16*)ws;
  _Float16* w0h = (_Float16*)(ws + 50331648);
  _Float16* w1h = (_Float16*)(ws + 50339840);
  _Float16* w2h = (_Float16*)(ws + 50372608);
  unsigned* hist = (unsigned*)(ws + 50405376);
  unsigned* cursor = (unsigned*)(ws + 50536448);
  unsigned* blocksum = (unsigned*)(ws + 50667520);
  unsigned* blockoff = (unsigned*)(ws + 50668032);
  float4* sorted = (float4*)(ws + 50668544);
  size_t need = 50668544 + (size_t)npts * 16;
  int use_sorted = (ws_size == 0 || ws_size >= need) ? 1 : 0;

  int fblk = (npts + 127) / 128;  // 128 pts per block (2 pairs)

  // D1: transpose (3072) + weights (144) + zero hist (128) = 3344 blocks
  prep_kernel<<<3344, 256, 0, stream>>>(planes, ph, w0, w1, w2, w0h, w1h, w2h,
                                        hist);
  // D2: cooperative hist+scan+scatter
  if (use_sorted) {
    void* args[] = {(void*)&coords,   (void*)&hist,     (void*)&cursor,
                    (void*)&blocksum, (void*)&blockoff, (void*)&sorted,
                    (void*)&npts};
    hipLaunchCooperativeKernel((const void*)sort_coop, dim3(1024), dim3(256),
                               args, 0, stream);
  }
  // D3: fused sample + MLP
  fused_kernel<<<fblk, 256, 0, stream>>>(coords, sorted, ph, w0h, w1h, w2h, b0,
                                         b1, b2, w3, b3, out, npts, use_sorted);
}

// Round 6
// 795.384 us; speedup vs baseline: 1.0061x; 1.0061x over previous
//
#include <hip/hip_runtime.h>
#include <hip/hip_cooperative_groups.h>

namespace cg = cooperative_groups;

// ---------------------------------------------------------------------------
// Triplane sample + 4-layer MLP, N=1e6 points. 3 dispatches:
//   D1 prep_kernel: [blocks 0..3071] transpose planes f32->f16 (x256, chan-
//       contiguous); [3072..3215] weights f32->f16; [3216..3343] zero hist.
//   D2 sort_coop (cooperative, 1024x256): Morton hist -> grid.sync ->
//       2-level scan -> grid.sync -> scatter (coords re-read, key recomputed).
//   D3 fused_kernel: sample 128 pts/block -> LDS feats -> pair-split MFMA MLP
//       -> out[orig_idx].
// Scale S=256 keeps f16 in normal range; epilogues add S*b in fp32; final
// layer divides by S in fp32.
//
// R1 (FAILED, 294us): 32-pt waves -> ILP collapse + 2x W traffic.
// R2 (NEUTRAL): pair-split 4 blk/CU; by-ref acc spilled (WRITE 70MB).
// R3 (NEUTRAL, 177us): de-spilled; mlp latency-chain bound, not occupancy.
// R4 (WIN, 598->509us): fused sample+MLP (238us vs 327us for the pair).
// R5 (FAILED, 800us): sort_coop cached points in regs ACROSS grid.sync ->
//   spilled everything (VGPR=16, WRITE 95MB, 390us). Rule: nothing lives
//   across grid.sync except index math.
// R6: sort_coop re-reads coords + recomputes key in scatter phase (12MB
//   L2-resident re-read ~ free). No state across syncs -> no spill.
// ---------------------------------------------------------------------------

#define SF 256.0f
#define HPAD 136  // halves per point-row in LDS H (128 + 8 pad), 16B aligned
#define FSTR 40   // halves per point-row for LDS feats overlay (32 + 8 pad)

typedef _Float16 half8 __attribute__((ext_vector_type(8)));
typedef _Float16 half4_t __attribute__((ext_vector_type(4)));
typedef float f32x4 __attribute__((ext_vector_type(4)));
typedef unsigned int u32x4 __attribute__((ext_vector_type(4)));

// ---------------- Morton key ----------------
__device__ inline unsigned spread5(unsigned v) {
  v &= 31u;
  v = (v | (v << 8)) & 0x100Fu;
  v = (v | (v << 4)) & 0x10C3u;
  v = (v | (v << 2)) & 0x1249u;
  return v;
}
__device__ inline unsigned cellkey(float x, float y, float z) {
  int qx = min(31, max(0, (int)((x + 1.0f) * 16.0f)));
  int qy = min(31, max(0, (int)((y + 1.0f) * 16.0f)));
  int qz = min(31, max(0, (int)((z + 1.0f) * 16.0f)));
  return spread5((unsigned)qx) | (spread5((unsigned)qy) << 1) |
         (spread5((unsigned)qz) << 2);
}

// ---------------- D1: prep (transpose + weights + zero hist) ----------------
__global__ __launch_bounds__(256) void prep_kernel(
    const float* __restrict__ planes, _Float16* __restrict__ ph,
    const float* __restrict__ w0, const float* __restrict__ w1,
    const float* __restrict__ w2, _Float16* __restrict__ w0h,
    _Float16* __restrict__ w1h, _Float16* __restrict__ w2h,
    unsigned* __restrict__ hist) {
  int bid = blockIdx.x;
  if (bid < 3072) {
    // plane transpose+convert+scale: 3*2^18 threads exactly
    int t = bid * 256 + threadIdx.x;
    int pid = t >> 18;
    int rem = t & ((1 << 18) - 1);              // y*512 + x
    const float* src = planes + ((size_t)pid << 23) + rem;  // [pid][c][y][x]
    union { _Float16 h[32]; u32x4 v[4]; } u;
#pragma unroll
    for (int c = 0; c < 32; c++)
      u.h[c] = (_Float16)(src[(size_t)c << 18] * SF);
    u32x4* dst = reinterpret_cast<u32x4*>(ph + ((size_t)t << 5));
#pragma unroll
    for (int i = 0; i < 4; i++) dst[i] = u.v[i];
  } else if (bid < 3216) {
    // weights f32 -> f16: 36864 threads exactly
    int t = (bid - 3072) * 256 + threadIdx.x;
    if (t < 4096) w0h[t] = (_Float16)w0[t];
    else if (t < 20480) w1h[t - 4096] = (_Float16)w1[t - 4096];
    else w2h[t - 20480] = (_Float16)w2[t - 20480];
  } else {
    // zero histogram: 128 blocks * 256 = 32768 exactly
    int t = (bid - 3216) * 256 + threadIdx.x;
    hist[t] = 0u;
  }
}

// ---------------- D2: cooperative hist + scan + scatter ----------------
// 1024 blocks x 256 threads. NO state lives across grid.sync (R5 lesson:
// reg-cached points spilled to scratch around the sync call boundary).
// Phase C re-reads coords (L2/L3-resident, 12MB) and recomputes keys.
__global__ __launch_bounds__(256) void sort_coop(
    const float* __restrict__ coords, unsigned* __restrict__ hist,
    unsigned* __restrict__ cursor, unsigned* __restrict__ blocksum,
    unsigned* __restrict__ blockoff, float4* __restrict__ sorted, int npts) {
  cg::grid_group grid = cg::this_grid();
  __shared__ unsigned s[256];
  int gtid = blockIdx.x * 256 + threadIdx.x;  // 262144 threads

  // ---- phase A: histogram ----
#pragma unroll
  for (int i = 0; i < 4; i++) {
    int p = i * 262144 + gtid;
    if (p < npts) {
      float x = coords[3 * (size_t)p + 0];
      float y = coords[3 * (size_t)p + 1];
      float z = coords[3 * (size_t)p + 2];
      atomicAdd(&hist[cellkey(x, y, z)], 1u);
    }
  }
  grid.sync();

  // ---- phase B1: blocks 0..127 exclusive-scan their 256-entry chunk ----
  if (blockIdx.x < 128) {
    int t = threadIdx.x;
    int base = blockIdx.x * 256;
    unsigned v = hist[base + t];
    s[t] = v;
    __syncthreads();
    for (int off = 1; off < 256; off <<= 1) {
      unsigned u = (t >= off) ? s[t - off] : 0u;
      __syncthreads();
      s[t] += u;
      __syncthreads();
    }
    cursor[base + t] = s[t] - v;  // within-chunk exclusive
    if (t == 255) blocksum[blockIdx.x] = s[255];
  }
  grid.sync();

  // ---- phase B2: block 0 exclusive-scans the 128 chunk totals ----
  if (blockIdx.x == 0) {
    int t = threadIdx.x;
    unsigned v2 = (t < 128) ? blocksum[t] : 0u;
    s[t] = v2;
    __syncthreads();
    for (int off = 1; off < 128; off <<= 1) {
      unsigned u = (t >= off) ? s[t - off] : 0u;
      __syncthreads();
      s[t] += u;
      __syncthreads();
    }
    if (t < 128) blockoff[t] = s[t] - v2;
  }
  grid.sync();

  // ---- phase C: re-read coords, recompute key, scatter ----
#pragma unroll
  for (int i = 0; i < 4; i++) {
    int p = i * 262144 + gtid;
    if (p < npts) {
      float x = coords[3 * (size_t)p + 0];
      float y = coords[3 * (size_t)p + 1];
      float z = coords[3 * (size_t)p + 2];
      unsigned k = cellkey(x, y, z);
      unsigned pos = atomicAdd(&cursor[k], 1u) + blockoff[k >> 8];
      float4 v;
      v.x = x; v.y = y; v.z = z;
      v.w = __uint_as_float((unsigned)p);
      sorted[pos] = v;
    }
  }
}

// ---------------- bilinear sampling: 16 channels (hf selects half) --------
__device__ __attribute__((always_inline)) inline void samp16(
    const _Float16* __restrict__ pl, float X, float Y, int hf, float* acc) {
  float fx = (X + 1.0f) * 0.5f * 511.0f;
  float fy = (Y + 1.0f) * 0.5f * 511.0f;
  float x0f = floorf(fx), y0f = floorf(fy);
  float wx1 = fx - x0f, wy1 = fy - y0f;
  float wx0 = 1.0f - wx1, wy0 = 1.0f - wy1;
  int x0 = (int)x0f, y0 = (int)y0f;
  int x1 = x0 + 1, y1 = y0 + 1;
  float vx0 = (x0 >= 0 && x0 < 512) ? 1.0f : 0.0f;
  float vx1 = (x1 >= 0 && x1 < 512) ? 1.0f : 0.0f;
  float vy0 = (y0 >= 0 && y0 < 512) ? 1.0f : 0.0f;
  float vy1 = (y1 >= 0 && y1 < 512) ? 1.0f : 0.0f;
  int xc0 = min(max(x0, 0), 511), xc1 = min(max(x1, 0), 511);
  int yc0 = min(max(y0, 0), 511), yc1 = min(max(y1, 0), 511);
  float w00 = wx0 * wy0 * vx0 * vy0, w10 = wx1 * wy0 * vx1 * vy0;
  float w01 = wx0 * wy1 * vx0 * vy1, w11 = wx1 * wy1 * vx1 * vy1;
  const _Float16* p00 = pl + ((((size_t)yc0 << 9) + xc0) << 5) + hf * 16;
  const _Float16* p10 = pl + ((((size_t)yc0 << 9) + xc1) << 5) + hf * 16;
  const _Float16* p01 = pl + ((((size_t)yc1 << 9) + xc0) << 5) + hf * 16;
  const _Float16* p11 = pl + ((((size_t)yc1 << 9) + xc1) << 5) + hf * 16;
#pragma unroll
  for (int ch = 0; ch < 2; ch++) {
    union { u32x4 v; _Float16 h[8]; } a, b, c, d;
    a.v = *reinterpret_cast<const u32x4*>(p00 + ch * 8);
    b.v = *reinterpret_cast<const u32x4*>(p10 + ch * 8);
    c.v = *reinterpret_cast<const u32x4*>(p01 + ch * 8);
    d.v = *reinterpret_cast<const u32x4*>(p11 + ch * 8);
#pragma unroll
    for (int j = 0; j < 8; j++) {
      acc[ch * 8 + j] += w00 * (float)a.h[j] + w10 * (float)b.h[j] +
                         w01 * (float)c.h[j] + w11 * (float)d.h[j];
    }
  }
}

// ---------------- D3: fused sample + MLP ----------------
// Block = 256 threads = 2 pairs = 128 points; LDS 34816 B -> 4 blocks/CU.
// Phase 1: 2 threads/pt sample 16ch each -> LDS feats (stride FSTR halves).
// Phase 2: pair-split MLP -- 2 waves share one 64-pt H buffer; wave w owns
//   hidden rows 64w..64w+63. Layer body is a MACRO (no call boundary), B
//   preloaded, per-mt fused epilogue: no spill, peak ~105 VGPR < 128 cap.
__device__ __attribute__((always_inline)) inline half8 ld16(const _Float16* p) {
  return *reinterpret_cast<const half8*>(p);
}

#define LAYER_PAIR(Wg, bias)                                                   \
  {                                                                            \
    half8 Bf[4][4]; /* [nt][ks] : 64 regs */                                   \
    _Pragma("unroll") for (int nt = 0; nt < 4; nt++)                           \
    _Pragma("unroll") for (int ks = 0; ks < 4; ks++)                           \
        Bf[nt][ks] = ld16(&H[(nt * 16 + n16) * HPAD + ks * 32 + g * 8]);       \
    __syncthreads(); /* all H reads done; safe to overwrite */                 \
    _Pragma("unroll") for (int mt = 0; mt < 4; mt++) {                         \
      f32x4 acc[4];                                                            \
      _Pragma("unroll") for (int nt = 0; nt < 4; nt++) acc[nt] = Z4;           \
      _Pragma("unroll") for (int ks = 0; ks < 4; ks++) {                       \
        half8 A = ld16((Wg) + ((w * 4 + mt) * 16 + n16) * 128 + ks * 32 + g * 8); \
        _Pragma("unroll") for (int nt = 0; nt < 4; nt++)                       \
            acc[nt] = __builtin_amdgcn_mfma_f32_16x16x32_f16(A, Bf[nt][ks],    \
                                                             acc[nt], 0, 0, 0); \
      }                                                                        \
      int gm = w * 4 + mt;                                                     \
      f32x4 bb = *reinterpret_cast<const f32x4*>((bias) + gm * 16 + g * 4);    \
      _Pragma("unroll") for (int nt = 0; nt < 4; nt++) {                       \
        half4_t v;                                                             \
        _Pragma("unroll") for (int r = 0; r < 4; r++)                          \
            v[r] = (_Float16)fmaxf(acc[nt][r] + SF * bb[r], 0.0f);             \
        *reinterpret_cast<half4_t*>(                                           \
            &H[(nt * 16 + n16) * HPAD + gm * 16 + g * 4]) = v;                 \
      }                                                                        \
    }                                                                          \
    __syncthreads(); /* H writes visible to partner */                         \
  }

__global__ __launch_bounds__(256, 4) void fused_kernel(
    const float* __restrict__ coords, const float4* __restrict__ sorted,
    const _Float16* __restrict__ ph, const _Float16* __restrict__ w0h,
    const _Float16* __restrict__ w1h, const _Float16* __restrict__ w2h,
    const float* __restrict__ b0, const float* __restrict__ b1,
    const float* __restrict__ b2, const float* __restrict__ w3,
    const float* __restrict__ b3, float* __restrict__ out, int npts,
    int use_sorted) {
  __shared__ alignas(16) _Float16 hbuf[2][64 * HPAD];  // 34816 B -> 4 blk/CU
  int tid = threadIdx.x;
  // XCD swizzle: contiguous Morton range per XCD for plane L2 locality.
  int nb = gridDim.x, bid = blockIdx.x;
  int per = nb >> 3;
  int sb = (bid < (per << 3)) ? ((bid & 7) * per + (bid >> 3)) : bid;

  // ---- phase 1: sample 128 points; 2 threads/pt, 16 channels each ----
  {
    int ptl = tid >> 1, hf = tid & 1;  // waves 0,1 cover pair0; 2,3 pair1
    long pb = (long)sb * 128 + (ptl >> 6) * 64;
    if (pb + 64 > npts) pb = npts - 64;  // tail: duplicate identical work
    long pp = pb + (ptl & 63);
    float cx, cy, cz;
    if (use_sorted) {
      float4 f = sorted[pp];
      cx = f.x; cy = f.y; cz = f.z;
    } else {
      cx = coords[3 * pp + 0];
      cy = coords[3 * pp + 1];
      cz = coords[3 * pp + 2];
    }
    float acc[16];
#pragma unroll
    for (int c = 0; c < 16; c++) acc[c] = 0.0f;
    samp16(ph, cx, cy, hf, acc);                  // plane 0: (x, y)
    samp16(ph + (1u << 23), cy, cz, hf, acc);     // plane 1: (y, z)
    samp16(ph + (2u << 23), cx, cz, hf, acc);     // plane 2: (x, z)
    union { _Float16 h[16]; u32x4 v[2]; } u;
#pragma unroll
    for (int c = 0; c < 16; c++) u.h[c] = (_Float16)acc[c];
    _Float16* F = hbuf[ptl >> 6];
    // feats row stride FSTR=40 halves (80B: 16B-aligned, bank-uniform)
    *reinterpret_cast<u32x4*>(&F[(ptl & 63) * FSTR + hf * 16]) = u.v[0];
    *reinterpret_cast<u32x4*>(&F[(ptl & 63) * FSTR + hf * 16 + 8]) = u.v[1];
  }
  __syncthreads();  // feats visible to all waves

  // ---- phase 2: pair-split MLP ----
  int wv = tid >> 6, lane = tid & 63;
  int pair = wv >> 1, w = wv & 1;
  int n16 = lane & 15, g = lane >> 4;
  long base = (long)sb * 128 + pair * 64;
  if (base + 64 > npts) base = npts - 64;  // same clamp as phase 1
  _Float16* H = hbuf[pair];
  const f32x4 Z4 = {0.0f, 0.0f, 0.0f, 0.0f};

  // layer 0: C^T = W0(rows 64w..64w+63, x32) * feats^T(32x64); K=32.
  {
    half8 Bf[4];
#pragma unroll
    for (int nt = 0; nt < 4; nt++)
      Bf[nt] = ld16(&H[(nt * 16 + n16) * FSTR + g * 8]);  // LDS feats
    __syncthreads();  // feats reads done; epilogue may overwrite region
#pragma unroll
    for (int mt = 0; mt < 4; mt++) {
      half8 A = ld16(w0h + ((w * 4 + mt) * 16 + n16) * 32 + g * 8);
      f32x4 acc[4];
#pragma unroll
      for (int nt = 0; nt < 4; nt++)
        acc[nt] = __builtin_amdgcn_mfma_f32_16x16x32_f16(A, Bf[nt], Z4, 0, 0, 0);
      int gm = w * 4 + mt;
      f32x4 bb = *reinterpret_cast<const f32x4*>(b0 + gm * 16 + g * 4);
#pragma unroll
      for (int nt = 0; nt < 4; nt++) {
        half4_t v;
#pragma unroll
        for (int r = 0; r < 4; r++)
          v[r] = (_Float16)fmaxf(acc[nt][r] + SF * bb[r], 0.0f);
        *reinterpret_cast<half4_t*>(
            &H[(nt * 16 + n16) * HPAD + gm * 16 + g * 4]) = v;
      }
    }
    __syncthreads();  // H(L0) visible before L1 reads
  }

  LAYER_PAIR(w1h, b1)
  LAYER_PAIR(w2h, b2)

  // layer 3: out = dot(h2, w3)/S + b3, fp32 VALU.
  // Pair covers 64 pts; wave w takes pts w*32..+31. lane = pt' + 32*half;
  // each half does 8 of 16 chunks, reduce across halves via shfl_xor(32).
  int ptl3 = lane & 31, hh = lane >> 5;
  int pt = w * 32 + ptl3;
  float o = 0.0f;
#pragma unroll
  for (int ii = 0; ii < 8; ii++) {
    int i = hh * 8 + ii;
    half8 hv = ld16(&H[pt * HPAD + i * 8]);
#pragma unroll
    for (int j = 0; j < 8; j++) o += (float)hv[j] * w3[i * 8 + j];
  }
  o += __shfl_xor(o, 32);
  if (lane < 32) {
    unsigned idx = use_sorted ? __float_as_uint(sorted[base + pt].w)
                              : (unsigned)(base + pt);
    out[idx] = o * (1.0f / SF) + b3[0];
  }
}

// ---------------- launch ----------------
extern "C" void kernel_launch(void* const* d_in, const int* in_sizes, int n_in,
                              void* d_out, int out_size, void* d_ws, size_t ws_size,
                              hipStream_t stream) {
  const float* coords = (const float*)d_in[0];
  const float* planes = (const float*)d_in[1];
  const float* w0 = (const float*)d_in[2];
  const float* b0 = (const float*)d_in[3];
  const float* w1 = (const float*)d_in[4];
  const float* b1 = (const float*)d_in[5];
  const float* w2 = (const float*)d_in[6];
  const float* b2 = (const float*)d_in[7];
  const float* w3 = (const float*)d_in[8];
  const float* b3 = (const float*)d_in[9];
  float* out = (float*)d_out;
  int npts = in_sizes[0] / 3;  // 1,000,000

  // workspace layout (bytes):
  //   ph       @ 0          50,331,648
  //   w0h      @ 50331648   8,192
  //   w1h      @ 50339840   32,768
  //   w2h      @ 50372608   32,768
  //   hist     @ 50405376   131,072
  //   cursor   @ 50536448   131,072
  //   blocksum @ 50667520   512
  //   blockoff @ 50668032   512
  //   sorted   @ 50668544   npts*16
  char* ws = (char*)d_ws;
  _Float16* ph = (_Float16*)ws;
  _Float16* w0h = (_Float16*)(ws + 50331648);
  _Float16* w1h = (_Float16*)(ws + 50339840);
  _Float16* w2h = (_Float16*)(ws + 50372608);
  unsigned* hist = (unsigned*)(ws + 50405376);
  unsigned* cursor = (unsigned*)(ws + 50536448);
  unsigned* blocksum = (unsigned*)(ws + 50667520);
  unsigned* blockoff = (unsigned*)(ws + 50668032);
  float4* sorted = (float4*)(ws + 50668544);
  size_t need = 50668544 + (size_t)npts * 16;
  int use_sorted = (ws_size == 0 || ws_size >= need) ? 1 : 0;

  int fblk = (npts + 127) / 128;  // 128 pts per block (2 pairs)

  // D1: transpose (3072) + weights (144) + zero hist (128) = 3344 blocks
  prep_kernel<<<3344, 256, 0, stream>>>(planes, ph, w0, w1, w2, w0h, w1h, w2h,
                                        hist);
  // D2: cooperative hist+scan+scatter
  if (use_sorted) {
    void* args[] = {(void*)&coords,   (void*)&hist,     (void*)&cursor,
                    (void*)&blocksum, (void*)&blockoff, (void*)&sorted,
                    (void*)&npts};
    hipLaunchCooperativeKernel((const void*)sort_coop, dim3(1024), dim3(256),
                               args, 0, stream);
  }
  // D3: fused sample + MLP
  fused_kernel<<<fblk, 256, 0, stream>>>(coords, sorted, ph, w0h, w1h, w2h, b0,
                                         b1, b2, w3, b3, out, npts, use_sorted);
}

// Round 7
// 446.246 us; speedup vs baseline: 1.7933x; 1.7824x over previous
//
#include <hip/hip_runtime.h>

// ---------------------------------------------------------------------------
// Triplane sample + 4-layer MLP, N=1e6 points. 2 dispatches:
//   D1 prep_kernel: [blocks 0..3071] transpose planes f32->f16 (x256, chan-
//       contiguous); [3072..3215] weights f32->f16.
//   D2 fused_kernel: sample 128 pts/block (original order) -> LDS feats ->
//       pair-split MFMA MLP -> out[p] (coalesced).
// Scale S=256 keeps f16 in normal range; epilogues add S*b in fp32; final
// layer divides by S in fp32.
//
// R1 (FAILED, 294us): 32-pt waves -> ILP collapse + 2x W traffic.
// R2 (NEUTRAL): pair-split 4 blk/CU; by-ref acc spilled (WRITE 70MB).
// R3 (NEUTRAL, 177us): de-spilled; mlp latency-chain bound, not occupancy.
// R4 (WIN, 598->509us): fused sample+MLP (238us vs 327us for the pair).
// R5 (FAILED, 800us): coop sort; blamed reg-spill across grid.sync.
// R6 (FAILED, 795us): spill removed, SAME 390us/0.5% VALUBusy/94MB writes ->
//   coop hist/scan/scatter is intrinsically stall-bound (grid barriers +
//   returning atomics). Abandon coop sort.
// R7: drop the Morton sort ENTIRELY. The f16 planes (48MB) are LLC-resident
//   (written LLC-warm by prep each iteration); unsorted texel gathers hit
//   LLC instead of L2 -- latency hidden by 16 waves/CU -- while HBM fetch
//   DROPS (sorted FETCH=166MB was cross-XCD plane re-fetch). Saves ~200us+
//   of sort work and all its launch gaps. 2 dispatches total.
// ---------------------------------------------------------------------------

#define SF 256.0f
#define HPAD 136  // halves per point-row in LDS H (128 + 8 pad), 16B aligned
#define FSTR 40   // halves per point-row for LDS feats overlay (32 + 8 pad)

typedef _Float16 half8 __attribute__((ext_vector_type(8)));
typedef _Float16 half4_t __attribute__((ext_vector_type(4)));
typedef float f32x4 __attribute__((ext_vector_type(4)));
typedef unsigned int u32x4 __attribute__((ext_vector_type(4)));

// ---------------- D1: prep (plane transpose + weights convert) -------------
__global__ __launch_bounds__(256) void prep_kernel(
    const float* __restrict__ planes, _Float16* __restrict__ ph,
    const float* __restrict__ w0, const float* __restrict__ w1,
    const float* __restrict__ w2, _Float16* __restrict__ w0h,
    _Float16* __restrict__ w1h, _Float16* __restrict__ w2h) {
  int bid = blockIdx.x;
  if (bid < 3072) {
    // plane transpose+convert+scale: 3*2^18 threads exactly
    int t = bid * 256 + threadIdx.x;
    int pid = t >> 18;
    int rem = t & ((1 << 18) - 1);              // y*512 + x
    const float* src = planes + ((size_t)pid << 23) + rem;  // [pid][c][y][x]
    union { _Float16 h[32]; u32x4 v[4]; } u;
#pragma unroll
    for (int c = 0; c < 32; c++)
      u.h[c] = (_Float16)(src[(size_t)c << 18] * SF);
    u32x4* dst = reinterpret_cast<u32x4*>(ph + ((size_t)t << 5));
#pragma unroll
    for (int i = 0; i < 4; i++) dst[i] = u.v[i];
  } else {
    // weights f32 -> f16: 36864 threads exactly (144 blocks)
    int t = (bid - 3072) * 256 + threadIdx.x;
    if (t < 4096) w0h[t] = (_Float16)w0[t];
    else if (t < 20480) w1h[t - 4096] = (_Float16)w1[t - 4096];
    else w2h[t - 20480] = (_Float16)w2[t - 20480];
  }
}

// ---------------- bilinear sampling: 16 channels (hf selects half) --------
__device__ __attribute__((always_inline)) inline void samp16(
    const _Float16* __restrict__ pl, float X, float Y, int hf, float* acc) {
  float fx = (X + 1.0f) * 0.5f * 511.0f;
  float fy = (Y + 1.0f) * 0.5f * 511.0f;
  float x0f = floorf(fx), y0f = floorf(fy);
  float wx1 = fx - x0f, wy1 = fy - y0f;
  float wx0 = 1.0f - wx1, wy0 = 1.0f - wy1;
  int x0 = (int)x0f, y0 = (int)y0f;
  int x1 = x0 + 1, y1 = y0 + 1;
  float vx0 = (x0 >= 0 && x0 < 512) ? 1.0f : 0.0f;
  float vx1 = (x1 >= 0 && x1 < 512) ? 1.0f : 0.0f;
  float vy0 = (y0 >= 0 && y0 < 512) ? 1.0f : 0.0f;
  float vy1 = (y1 >= 0 && y1 < 512) ? 1.0f : 0.0f;
  int xc0 = min(max(x0, 0), 511), xc1 = min(max(x1, 0), 511);
  int yc0 = min(max(y0, 0), 511), yc1 = min(max(y1, 0), 511);
  float w00 = wx0 * wy0 * vx0 * vy0, w10 = wx1 * wy0 * vx1 * vy0;
  float w01 = wx0 * wy1 * vx0 * vy1, w11 = wx1 * wy1 * vx1 * vy1;
  const _Float16* p00 = pl + ((((size_t)yc0 << 9) + xc0) << 5) + hf * 16;
  const _Float16* p10 = pl + ((((size_t)yc0 << 9) + xc1) << 5) + hf * 16;
  const _Float16* p01 = pl + ((((size_t)yc1 << 9) + xc0) << 5) + hf * 16;
  const _Float16* p11 = pl + ((((size_t)yc1 << 9) + xc1) << 5) + hf * 16;
#pragma unroll
  for (int ch = 0; ch < 2; ch++) {
    union { u32x4 v; _Float16 h[8]; } a, b, c, d;
    a.v = *reinterpret_cast<const u32x4*>(p00 + ch * 8);
    b.v = *reinterpret_cast<const u32x4*>(p10 + ch * 8);
    c.v = *reinterpret_cast<const u32x4*>(p01 + ch * 8);
    d.v = *reinterpret_cast<const u32x4*>(p11 + ch * 8);
#pragma unroll
    for (int j = 0; j < 8; j++) {
      acc[ch * 8 + j] += w00 * (float)a.h[j] + w10 * (float)b.h[j] +
                         w01 * (float)c.h[j] + w11 * (float)d.h[j];
    }
  }
}

// ---------------- D2: fused sample + MLP ----------------
// Block = 256 threads = 2 pairs = 128 points; LDS 34816 B -> 4 blocks/CU.
// Phase 1: 2 threads/pt sample 16ch each -> LDS feats (stride FSTR halves).
// Phase 2: pair-split MLP -- 2 waves share one 64-pt H buffer; wave w owns
//   hidden rows 64w..64w+63. Layer body is a MACRO (no call boundary), B
//   preloaded, per-mt fused epilogue: no spill, peak ~105 VGPR < 128 cap.
__device__ __attribute__((always_inline)) inline half8 ld16(const _Float16* p) {
  return *reinterpret_cast<const half8*>(p);
}

#define LAYER_PAIR(Wg, bias)                                                   \
  {                                                                            \
    half8 Bf[4][4]; /* [nt][ks] : 64 regs */                                   \
    _Pragma("unroll") for (int nt = 0; nt < 4; nt++)                           \
    _Pragma("unroll") for (int ks = 0; ks < 4; ks++)                           \
        Bf[nt][ks] = ld16(&H[(nt * 16 + n16) * HPAD + ks * 32 + g * 8]);       \
    __syncthreads(); /* all H reads done; safe to overwrite */                 \
    _Pragma("unroll") for (int mt = 0; mt < 4; mt++) {                         \
      f32x4 acc[4];                                                            \
      _Pragma("unroll") for (int nt = 0; nt < 4; nt++) acc[nt] = Z4;           \
      _Pragma("unroll") for (int ks = 0; ks < 4; ks++) {                       \
        half8 A = ld16((Wg) + ((w * 4 + mt) * 16 + n16) * 128 + ks * 32 + g * 8); \
        _Pragma("unroll") for (int nt = 0; nt < 4; nt++)                       \
            acc[nt] = __builtin_amdgcn_mfma_f32_16x16x32_f16(A, Bf[nt][ks],    \
                                                             acc[nt], 0, 0, 0); \
      }                                                                        \
      int gm = w * 4 + mt;                                                     \
      f32x4 bb = *reinterpret_cast<const f32x4*>((bias) + gm * 16 + g * 4);    \
      _Pragma("unroll") for (int nt = 0; nt < 4; nt++) {                       \
        half4_t v;                                                             \
        _Pragma("unroll") for (int r = 0; r < 4; r++)                          \
            v[r] = (_Float16)fmaxf(acc[nt][r] + SF * bb[r], 0.0f);             \
        *reinterpret_cast<half4_t*>(                                           \
            &H[(nt * 16 + n16) * HPAD + gm * 16 + g * 4]) = v;                 \
      }                                                                        \
    }                                                                          \
    __syncthreads(); /* H writes visible to partner */                         \
  }

__global__ __launch_bounds__(256, 4) void fused_kernel(
    const float* __restrict__ coords, const _Float16* __restrict__ ph,
    const _Float16* __restrict__ w0h, const _Float16* __restrict__ w1h,
    const _Float16* __restrict__ w2h, const float* __restrict__ b0,
    const float* __restrict__ b1, const float* __restrict__ b2,
    const float* __restrict__ w3, const float* __restrict__ b3,
    float* __restrict__ out, int npts) {
  __shared__ alignas(16) _Float16 hbuf[2][64 * HPAD];  // 34816 B -> 4 blk/CU
  int tid = threadIdx.x;
  int sb = blockIdx.x;  // natural order: coalesced coords reads + out writes

  // ---- phase 1: sample 128 points; 2 threads/pt, 16 channels each ----
  {
    int ptl = tid >> 1, hf = tid & 1;  // waves 0,1 cover pair0; 2,3 pair1
    long pb = (long)sb * 128 + (ptl >> 6) * 64;
    if (pb + 64 > npts) pb = npts - 64;  // tail: duplicate identical work
    long pp = pb + (ptl & 63);
    float cx = coords[3 * pp + 0];
    float cy = coords[3 * pp + 1];
    float cz = coords[3 * pp + 2];
    float acc[16];
#pragma unroll
    for (int c = 0; c < 16; c++) acc[c] = 0.0f;
    samp16(ph, cx, cy, hf, acc);                  // plane 0: (x, y)
    samp16(ph + (1u << 23), cy, cz, hf, acc);     // plane 1: (y, z)
    samp16(ph + (2u << 23), cx, cz, hf, acc);     // plane 2: (x, z)
    union { _Float16 h[16]; u32x4 v[2]; } u;
#pragma unroll
    for (int c = 0; c < 16; c++) u.h[c] = (_Float16)acc[c];
    _Float16* F = hbuf[ptl >> 6];
    // feats row stride FSTR=40 halves (80B: 16B-aligned, bank-uniform)
    *reinterpret_cast<u32x4*>(&F[(ptl & 63) * FSTR + hf * 16]) = u.v[0];
    *reinterpret_cast<u32x4*>(&F[(ptl & 63) * FSTR + hf * 16 + 8]) = u.v[1];
  }
  __syncthreads();  // feats visible to all waves

  // ---- phase 2: pair-split MLP ----
  int wv = tid >> 6, lane = tid & 63;
  int pair = wv >> 1, w = wv & 1;
  int n16 = lane & 15, g = lane >> 4;
  long base = (long)sb * 128 + pair * 64;
  if (base + 64 > npts) base = npts - 64;  // same clamp as phase 1
  _Float16* H = hbuf[pair];
  const f32x4 Z4 = {0.0f, 0.0f, 0.0f, 0.0f};

  // layer 0: C^T = W0(rows 64w..64w+63, x32) * feats^T(32x64); K=32.
  {
    half8 Bf[4];
#pragma unroll
    for (int nt = 0; nt < 4; nt++)
      Bf[nt] = ld16(&H[(nt * 16 + n16) * FSTR + g * 8]);  // LDS feats
    __syncthreads();  // feats reads done; epilogue may overwrite region
#pragma unroll
    for (int mt = 0; mt < 4; mt++) {
      half8 A = ld16(w0h + ((w * 4 + mt) * 16 + n16) * 32 + g * 8);
      f32x4 acc[4];
#pragma unroll
      for (int nt = 0; nt < 4; nt++)
        acc[nt] = __builtin_amdgcn_mfma_f32_16x16x32_f16(A, Bf[nt], Z4, 0, 0, 0);
      int gm = w * 4 + mt;
      f32x4 bb = *reinterpret_cast<const f32x4*>(b0 + gm * 16 + g * 4);
#pragma unroll
      for (int nt = 0; nt < 4; nt++) {
        half4_t v;
#pragma unroll
        for (int r = 0; r < 4; r++)
          v[r] = (_Float16)fmaxf(acc[nt][r] + SF * bb[r], 0.0f);
        *reinterpret_cast<half4_t*>(
            &H[(nt * 16 + n16) * HPAD + gm * 16 + g * 4]) = v;
      }
    }
    __syncthreads();  // H(L0) visible before L1 reads
  }

  LAYER_PAIR(w1h, b1)
  LAYER_PAIR(w2h, b2)

  // layer 3: out = dot(h2, w3)/S + b3, fp32 VALU.
  // Pair covers 64 pts; wave w takes pts w*32..+31. lane = pt' + 32*half;
  // each half does 8 of 16 chunks, reduce across halves via shfl_xor(32).
  int ptl3 = lane & 31, hh = lane >> 5;
  int pt = w * 32 + ptl3;
  float o = 0.0f;
#pragma unroll
  for (int ii = 0; ii < 8; ii++) {
    int i = hh * 8 + ii;
    half8 hv = ld16(&H[pt * HPAD + i * 8]);
#pragma unroll
    for (int j = 0; j < 8; j++) o += (float)hv[j] * w3[i * 8 + j];
  }
  o += __shfl_xor(o, 32);
  if (lane < 32) {
    out[base + pt] = o * (1.0f / SF) + b3[0];  // coalesced
  }
}

// ---------------- launch ----------------
extern "C" void kernel_launch(void* const* d_in, const int* in_sizes, int n_in,
                              void* d_out, int out_size, void* d_ws, size_t ws_size,
                              hipStream_t stream) {
  const float* coords = (const float*)d_in[0];
  const float* planes = (const float*)d_in[1];
  const float* w0 = (const float*)d_in[2];
  const float* b0 = (const float*)d_in[3];
  const float* w1 = (const float*)d_in[4];
  const float* b1 = (const float*)d_in[5];
  const float* w2 = (const float*)d_in[6];
  const float* b2 = (const float*)d_in[7];
  const float* w3 = (const float*)d_in[8];
  const float* b3 = (const float*)d_in[9];
  float* out = (float*)d_out;
  int npts = in_sizes[0] / 3;  // 1,000,000

  // workspace layout (bytes):
  //   ph       @ 0          50,331,648
  //   w0h      @ 50331648   8,192
  //   w1h      @ 50339840   32,768
  //   w2h      @ 50372608   32,768
  char* ws = (char*)d_ws;
  _Float16* ph = (_Float16*)ws;
  _Float16* w0h = (_Float16*)(ws + 50331648);
  _Float16* w1h = (_Float16*)(ws + 50339840);
  _Float16* w2h = (_Float16*)(ws + 50372608);

  int fblk = (npts + 127) / 128;  // 128 pts per block (2 pairs)

  // D1: transpose (3072) + weights (144) = 3216 blocks
  prep_kernel<<<3216, 256, 0, stream>>>(planes, ph, w0, w1, w2, w0h, w1h, w2h);
  // D2: fused sample + MLP, original point order
  fused_kernel<<<fblk, 256, 0, stream>>>(coords, ph, w0h, w1h, w2h, b0, b1, b2,
                                         w3, b3, out, npts);
}